// Round 1
// baseline (521.661 us; speedup 1.0000x reference)
//
#include <hip/hip_runtime.h>
#include <hip/hip_bf16.h>

// messages = relu(concat(node[src], node[tgt], edge) @ W + b)  -> segment_sum by tgt
// Strategy: bf16 MFMA gather-GEMM (16x16x32), f32 accumulate, atomic scatter.

using s16x8 = __attribute__((ext_vector_type(8))) short;
using f32x4 = __attribute__((ext_vector_type(4))) float;

static __device__ __forceinline__ ushort f2bf(float f) {
    union { __hip_bfloat16 h; ushort u; } cv;
    cv.h = __float2bfloat16(f);
    return cv.u;
}

// Transpose + convert W[192][64] f32 -> WT[64][192] bf16 (in workspace).
__global__ void prep_wt(const float* __restrict__ W, ushort* __restrict__ WT) {
    int idx = blockIdx.x * blockDim.x + threadIdx.x;   // idx = n*192 + k
    if (idx < 64 * 192) {
        int n = idx / 192;
        int k = idx % 192;
        WT[idx] = f2bf(W[k * 64 + n]);
    }
}

__global__ __launch_bounds__(256) void edge_gemm(
    const float* __restrict__ node, const float* __restrict__ edgef,
    const int* __restrict__ src, const int* __restrict__ tgt,
    const ushort* __restrict__ WT, const float* __restrict__ bias,
    float* __restrict__ out, int n_edges)
{
    // Per-wave private A tile: 16 edges x 192 K, bf16, padded 192->200 to break
    // the 96-dword row stride (bank-conflict fix, G4).
    __shared__ __align__(16) ushort A[4][16][200];

    const int wave = threadIdx.x >> 6;
    const int lane = threadIdx.x & 63;
    const int g = lane >> 4;   // k-group 0..3
    const int r = lane & 15;   // row/col within fragment

    // B fragments: Bf[nt][ks], lane holds WT[nt*16+r][ks*32+g*8 .. +8)
    s16x8 Bf[4][6];
#pragma unroll
    for (int nt = 0; nt < 4; ++nt) {
#pragma unroll
        for (int ks = 0; ks < 6; ++ks) {
            const int n = nt * 16 + r;
            const int k0 = ks * 32 + g * 8;
            Bf[nt][ks] = *reinterpret_cast<const s16x8*>(WT + n * 192 + k0);
        }
    }
    float bv[4];
#pragma unroll
    for (int nt = 0; nt < 4; ++nt) bv[nt] = bias[nt * 16 + r];

    const int tile0 = blockIdx.x * 64 + wave * 16;   // first edge of this wave's tile

    // ---- Stage A: gather src/tgt/edge rows, cvt f32->bf16, write LDS ----
#pragma unroll
    for (int seg = 0; seg < 3; ++seg) {
#pragma unroll
        for (int i = 0; i < 4; ++i) {
            const int el = i * 4 + g;          // local edge 0..15
            const int e = tile0 + el;
            const int ee = (e < n_edges) ? e : 0;
            const float* p;
            if (seg == 0)      p = node + (size_t)src[ee] * 64;
            else if (seg == 1) p = node + (size_t)tgt[ee] * 64;
            else               p = edgef + (size_t)ee * 64;
            const f32x4 v = *reinterpret_cast<const f32x4*>(p + r * 4);
            ushort4 h;
            h.x = f2bf(v[0]); h.y = f2bf(v[1]); h.z = f2bf(v[2]); h.w = f2bf(v[3]);
            *reinterpret_cast<ushort4*>(&A[wave][el][seg * 64 + r * 4]) = h;
        }
    }
    __syncthreads();

    // ---- MFMA main loop: 6 k-steps x 4 n-tiles ----
    f32x4 acc[4] = {{0.f,0.f,0.f,0.f},{0.f,0.f,0.f,0.f},{0.f,0.f,0.f,0.f},{0.f,0.f,0.f,0.f}};
#pragma unroll
    for (int ks = 0; ks < 6; ++ks) {
        const s16x8 a = *reinterpret_cast<const s16x8*>(&A[wave][r][ks * 32 + g * 8]);
#pragma unroll
        for (int nt = 0; nt < 4; ++nt) {
            acc[nt] = __builtin_amdgcn_mfma_f32_16x16x32_bf16(a, Bf[nt][ks], acc[nt], 0, 0, 0);
        }
    }

    // ---- Epilogue: relu(acc + b), atomic scatter to out[tgt] ----
    // C/D layout (HW-verified): col = lane&15, row = (lane>>4)*4 + j
#pragma unroll
    for (int nt = 0; nt < 4; ++nt) {
        const int n = nt * 16 + r;
#pragma unroll
        for (int j = 0; j < 4; ++j) {
            const int row = g * 4 + j;
            const int e = tile0 + row;
            if (e < n_edges) {
                float v = fmaxf(acc[nt][j] + bv[nt], 0.0f);
                const int t = tgt[e];
                unsafeAtomicAdd(out + (size_t)t * 64 + n, v);
            }
        }
    }
}

extern "C" void kernel_launch(void* const* d_in, const int* in_sizes, int n_in,
                              void* d_out, int out_size, void* d_ws, size_t ws_size,
                              hipStream_t stream) {
    const float* node  = (const float*)d_in[0];
    const float* edgef = (const float*)d_in[1];
    const int*   src   = (const int*)d_in[2];
    const int*   tgt   = (const int*)d_in[3];
    const float* W     = (const float*)d_in[4];
    const float* bias  = (const float*)d_in[5];
    float* out = (float*)d_out;
    const int n_edges = in_sizes[2];

    ushort* WT = (ushort*)d_ws;   // 64*192*2 = 24.6 KB

    hipMemsetAsync(d_out, 0, (size_t)out_size * sizeof(float), stream);
    prep_wt<<<48, 256, 0, stream>>>(W, WT);

    const int tiles = (n_edges + 63) / 64;
    edge_gemm<<<tiles, 256, 0, stream>>>(node, edgef, src, tgt, WT, bias, out, n_edges);
}